// Round 1
// baseline (1407.947 us; speedup 1.0000x reference)
//
#include <hip/hip_runtime.h>
#include <hip/hip_bf16.h>

#define HH 64
#define XDIM 896
#define FF 512
#define LL 6
#define CC 40

typedef __bf16 bf16x8 __attribute__((ext_vector_type(8)));
typedef float f32x4 __attribute__((ext_vector_type(4)));

__device__ __forceinline__ float bf2f(unsigned short u){
  union{unsigned int u; float f;} v; v.u = ((unsigned int)u)<<16; return v.f;
}
__device__ __forceinline__ unsigned short f2bf(float f){
  union{float f; unsigned int u;} v; v.f=f; unsigned int u=v.u;
  return (unsigned short)((u + 0x7fffu + ((u>>16)&1u))>>16);
}

// ---- degree count ----
__global__ void __launch_bounds__(256) k_count(const int* __restrict__ ei, int E, int* __restrict__ cnt){
  int i = blockIdx.x*blockDim.x + threadIdx.x;
  int stride = gridDim.x*blockDim.x;
  for (; i < E; i += stride) atomicAdd(&cnt[ei[E+i]], 1);
}

__global__ void __launch_bounds__(256) k_dinv(const int* __restrict__ cnt, float* __restrict__ dinv, int N){
  int i = blockIdx.x*blockDim.x + threadIdx.x;
  if (i < N) dinv[i] = rsqrtf((float)(cnt[i]+1));
}

// ---- exclusive scan (3-phase) ----
__global__ void __launch_bounds__(256) k_scan1(const int* __restrict__ cnt, int* __restrict__ offs,
                                               int* __restrict__ bsum, int N){
  __shared__ int s[256];
  int t=threadIdx.x, gid=blockIdx.x*256+t;
  int v = (gid<N)? cnt[gid] : 0;
  s[t]=v; __syncthreads();
  for (int o=1;o<256;o<<=1){ int x=(t>=o)?s[t-o]:0; __syncthreads(); s[t]+=x; __syncthreads(); }
  if (gid<N) offs[gid]=s[t]-v;
  if (t==255) bsum[blockIdx.x]=s[t];
}

__global__ void __launch_bounds__(512) k_scan2(int* __restrict__ bsum, int nb){
  __shared__ int s[512];
  int t=threadIdx.x;
  int v=(t<nb)?bsum[t]:0; s[t]=v; __syncthreads();
  for(int o=1;o<512;o<<=1){ int x=(t>=o)?s[t-o]:0; __syncthreads(); s[t]+=x; __syncthreads(); }
  if (t<nb) bsum[t]=s[t]-v;
}

__global__ void __launch_bounds__(256) k_scan3(int* __restrict__ offs, const int* __restrict__ bsum,
                                               int* __restrict__ cur, int N, int E){
  int gid=blockIdx.x*256+threadIdx.x;
  if (gid<N){ int o=offs[gid]+bsum[gid>>8]; offs[gid]=o; cur[gid]=o; }
  if (gid==0) offs[N]=E;
}

// ---- CSR fill (sorted by col) ----
__global__ void __launch_bounds__(256) k_fill(const int* __restrict__ ei, int E, const float* __restrict__ dinv,
                                              int* __restrict__ cur, int* __restrict__ esrc, float* __restrict__ ew){
  int i = blockIdx.x*blockDim.x + threadIdx.x;
  int stride = gridDim.x*blockDim.x;
  for (; i<E; i+=stride){
    int r = ei[i], c = ei[E+i];
    int pos = atomicAdd(&cur[c],1);
    esrc[pos]=r; ew[pos]=dinv[r]*dinv[c];
  }
}

// ---- x -> bf16 into X[:, 0:512] ----
__global__ void __launch_bounds__(256) k_xcast(const float* __restrict__ x, unsigned short* __restrict__ X, int N){
  int i = blockIdx.x*blockDim.x + threadIdx.x; // one thread per 4 floats
  int total = N*(FF/4);
  if (i >= total) return;
  int row = i/(FF/4), c4 = (i%(FF/4))*4;
  float4 v = *(const float4*)(x + (size_t)row*FF + c4);
  ushort4 o; o.x=f2bf(v.x); o.y=f2bf(v.y); o.z=f2bf(v.z); o.w=f2bf(v.w);
  *(ushort4*)(X + (size_t)row*XDIM + c4) = o;
}

// ---- W (fp32 [d][ncols]) -> bf16 MFMA B-fragment layout [kb][nt][lane][8] ----
__global__ void __launch_bounds__(256) k_wfrag(const float* __restrict__ W, unsigned short* __restrict__ dst,
                                               int d, int ntile, int ncols){
  int idx = blockIdx.x*blockDim.x + threadIdx.x;
  int total = (d>>5)*ntile*512;
  if (idx>=total) return;
  int j = idx&7, lane=(idx>>3)&63, rem=idx>>9;
  int nt = rem % ntile, kb = rem / ntile;
  int k = kb*32 + (lane>>4)*8 + j;
  int c = nt*16 + (lane&15);
  float v = (c<ncols)? W[(size_t)k*ncols + c] : 0.f;
  dst[idx]=f2bf(v);
}

// ---- lin[N,64] = X[:, :32*nkb] @ Wf ; 4 waves/block, 16 rows/wave ----
__global__ void __launch_bounds__(256) k_gemm(const unsigned short* __restrict__ X,
                                              const unsigned short* __restrict__ Wf,
                                              unsigned short* __restrict__ lin,
                                              int N, int nkb){
  int lane = threadIdx.x & 63, wid = threadIdx.x >> 6;
  long row0 = (long)blockIdx.x*64 + wid*16;
  int arow = lane & 15, kgrp = lane >> 4;
  long r = row0 + arow; if (r > (long)N-1) r = N-1;
  const unsigned short* aptr = X + (size_t)r*XDIM + kgrp*8;
  const unsigned short* bptr = Wf + lane*8;
  f32x4 acc0 = {0.f,0.f,0.f,0.f}, acc1 = acc0, acc2 = acc0, acc3 = acc0;
  for (int kb=0; kb<nkb; ++kb){
    bf16x8 a = *(const bf16x8*)(aptr + (size_t)kb*32);
    const unsigned short* bp = bptr + (size_t)kb*2048;
    bf16x8 b0=*(const bf16x8*)bp, b1=*(const bf16x8*)(bp+512),
           b2=*(const bf16x8*)(bp+1024), b3=*(const bf16x8*)(bp+1536);
    acc0=__builtin_amdgcn_mfma_f32_16x16x32_bf16(a,b0,acc0,0,0,0);
    acc1=__builtin_amdgcn_mfma_f32_16x16x32_bf16(a,b1,acc1,0,0,0);
    acc2=__builtin_amdgcn_mfma_f32_16x16x32_bf16(a,b2,acc2,0,0,0);
    acc3=__builtin_amdgcn_mfma_f32_16x16x32_bf16(a,b3,acc3,0,0,0);
  }
  // D: col = lane&15, row = (lane>>4)*4 + reg
  for (int j=0;j<4;++j){
    long rr = row0 + kgrp*4 + j;
    if (rr < N){
      unsigned short* lp = lin + (size_t)rr*64 + arow;
      lp[0]  = f2bf(acc0[j]);
      lp[16] = f2bf(acc1[j]);
      lp[32] = f2bf(acc2[j]);
      lp[48] = f2bf(acc3[j]);
    }
  }
}

// ---- aggregate: 1 wave per node, lane = feature ----
__global__ void __launch_bounds__(256) k_agg(const unsigned short* __restrict__ lin,
                                             const int* __restrict__ offs,
                                             const int* __restrict__ esrc,
                                             const float* __restrict__ ew,
                                             const float* __restrict__ dinv,
                                             const float* __restrict__ bias,
                                             unsigned short* __restrict__ X,
                                             int colbase, int N){
  int lane = threadIdx.x & 63, wid = threadIdx.x >> 6;
  int n = blockIdx.x*4 + wid;
  if (n >= N) return;
  float dv = dinv[n];
  float acc = dv*dv*bf2f(lin[(size_t)n*64 + lane]);   // self-loop
  int s = offs[n], e = offs[n+1];
  for (int i=s; i<e; ++i){
    int src = esrc[i];
    acc += ew[i]*bf2f(lin[(size_t)src*64 + lane]);
  }
  float h = fmaxf(acc + bias[lane], 0.f);
  X[(size_t)n*XDIM + colbase + lane] = f2bf(h);
}

// ---- final: logits = X @ Wlin + blin, log_softmax, write fp32 [N,40] ----
__global__ void __launch_bounds__(256) k_final(const unsigned short* __restrict__ X,
                                               const unsigned short* __restrict__ Wf,
                                               const float* __restrict__ blin,
                                               float* __restrict__ out, int N){
  int lane=threadIdx.x&63, wid=threadIdx.x>>6;
  long row0=(long)blockIdx.x*64 + wid*16;
  int c0=lane&15, g=lane>>4;
  long r=row0+c0; if (r > (long)N-1) r = N-1;
  const unsigned short* aptr = X + (size_t)r*XDIM + g*8;
  const unsigned short* bptr = Wf + lane*8;
  f32x4 acc0={0.f,0.f,0.f,0.f}, acc1=acc0, acc2=acc0;
  const int nkb = XDIM/32; // 28
  for (int kb=0;kb<nkb;++kb){
    bf16x8 a=*(const bf16x8*)(aptr+(size_t)kb*32);
    const unsigned short* bp = bptr + (size_t)kb*1536;
    bf16x8 b0=*(const bf16x8*)bp, b1=*(const bf16x8*)(bp+512), b2=*(const bf16x8*)(bp+1024);
    acc0=__builtin_amdgcn_mfma_f32_16x16x32_bf16(a,b0,acc0,0,0,0);
    acc1=__builtin_amdgcn_mfma_f32_16x16x32_bf16(a,b1,acc1,0,0,0);
    acc2=__builtin_amdgcn_mfma_f32_16x16x32_bf16(a,b2,acc2,0,0,0);
  }
  float bl0 = blin[c0], bl1 = blin[16+c0];
  bool v2ok = (c0 < 8);
  float bl2 = v2ok ? blin[32+c0] : 0.f;
  for (int j=0;j<4;++j){
    long rr = row0 + g*4 + j;
    float v0 = acc0[j]+bl0, v1 = acc1[j]+bl1;
    float v2 = v2ok ? (acc2[j]+bl2) : -1e30f;
    float m = fmaxf(fmaxf(v0,v1),v2);
    m = fmaxf(m, __shfl_xor(m,1,64));
    m = fmaxf(m, __shfl_xor(m,2,64));
    m = fmaxf(m, __shfl_xor(m,4,64));
    m = fmaxf(m, __shfl_xor(m,8,64));
    float sEx = expf(v0-m)+expf(v1-m)+(v2ok?expf(v2-m):0.f);
    sEx += __shfl_xor(sEx,1,64);
    sEx += __shfl_xor(sEx,2,64);
    sEx += __shfl_xor(sEx,4,64);
    sEx += __shfl_xor(sEx,8,64);
    float lse = m + logf(sEx);
    if (rr < N){
      out[(size_t)rr*CC + c0]      = v0 - lse;
      out[(size_t)rr*CC + 16 + c0] = v1 - lse;
      if (v2ok) out[(size_t)rr*CC + 32 + c0] = v2 - lse;
    }
  }
}

extern "C" void kernel_launch(void* const* d_in, const int* in_sizes, int n_in,
                              void* d_out, int out_size, void* d_ws, size_t ws_size,
                              hipStream_t stream){
  const float* x = (const float*)d_in[0];
  const int* ei = (const int*)d_in[1];
  const float* Wl[LL]; const float* bl[LL];
  for (int i=0;i<LL;i++){ Wl[i]=(const float*)d_in[2+2*i]; bl[i]=(const float*)d_in[3+2*i]; }
  const float* Wlin = (const float*)d_in[2+2*LL];
  const float* blin = (const float*)d_in[3+2*LL];
  float* out = (float*)d_out;
  const int N = in_sizes[0]/FF;
  const int E = in_sizes[1]/2;

  char* p = (char*)d_ws;
  auto alloc = [&](size_t b)->char*{ char* r=p; p += (b+255)&~(size_t)255; return r; };
  unsigned short* X   = (unsigned short*)alloc((size_t)N*XDIM*2);
  unsigned short* lin = (unsigned short*)alloc((size_t)N*64*2);
  unsigned short* WfL[LL];
  for (int i=0;i<LL;i++){ int d=FF+HH*i; WfL[i]=(unsigned short*)alloc((size_t)d*64*2); }
  unsigned short* WfLin = (unsigned short*)alloc((size_t)XDIM*48*2);
  float* dinv = (float*)alloc((size_t)N*4);
  int* cnt    = (int*)alloc((size_t)N*4);
  int* offs   = (int*)alloc((size_t)(N+1)*4);
  int* cur    = (int*)alloc((size_t)N*4);
  int* bsum   = (int*)alloc(512*4);
  int* esrc   = (int*)alloc((size_t)E*4);
  float* ew   = (float*)alloc((size_t)E*4);

  hipMemsetAsync(cnt, 0, (size_t)N*4, stream);

  int nb = (N+255)/256;
  k_count<<<2048, 256, 0, stream>>>(ei, E, cnt);
  k_dinv <<<nb, 256, 0, stream>>>(cnt, dinv, N);
  k_scan1<<<nb, 256, 0, stream>>>(cnt, offs, bsum, N);
  k_scan2<<<1, 512, 0, stream>>>(bsum, nb);
  k_scan3<<<nb, 256, 0, stream>>>(offs, bsum, cur, N, E);
  k_fill <<<2048, 256, 0, stream>>>(ei, E, dinv, cur, esrc, ew);
  k_xcast<<<(N*(FF/4)+255)/256, 256, 0, stream>>>(x, X, N);
  for (int i=0;i<LL;i++){
    int d = FF+HH*i;
    int tot = (d>>5)*4*512;
    k_wfrag<<<(tot+255)/256,256,0,stream>>>(Wl[i], WfL[i], d, 4, HH);
  }
  { int tot = (XDIM>>5)*3*512;
    k_wfrag<<<(tot+255)/256,256,0,stream>>>(Wlin, WfLin, XDIM, 3, CC); }

  int gb = (N+63)/64;
  int ab = (N+3)/4;
  for (int i=0;i<LL;i++){
    k_gemm<<<gb,256,0,stream>>>(X, WfL[i], lin, N, (FF+HH*i)>>5);
    k_agg <<<ab,256,0,stream>>>(lin, offs, esrc, ew, dinv, bl[i], X, FF+HH*i, N);
  }
  k_final<<<gb,256,0,stream>>>(X, WfLin, blin, out, N);
}

// Round 2
// 871.634 us; speedup vs baseline: 1.6153x; 1.6153x over previous
//
#include <hip/hip_runtime.h>
#include <hip/hip_bf16.h>

#define HH 64
#define XDIM 896
#define FF 512
#define LL 6
#define CC 40

typedef __bf16 bf16x8 __attribute__((ext_vector_type(8)));
typedef float f32x4 __attribute__((ext_vector_type(4)));

__device__ __forceinline__ float bf2f(unsigned short u){
  union{unsigned int u; float f;} v; v.u = ((unsigned int)u)<<16; return v.f;
}
__device__ __forceinline__ unsigned short f2bf(float f){
  union{float f; unsigned int u;} v; v.f=f; unsigned int u=v.u;
  return (unsigned short)((u + 0x7fffu + ((u>>16)&1u))>>16);
}

// ---- degree count ----
__global__ void __launch_bounds__(256) k_count(const int* __restrict__ ei, int E, int* __restrict__ cnt){
  int i = blockIdx.x*blockDim.x + threadIdx.x;
  int stride = gridDim.x*blockDim.x;
  for (; i < E; i += stride) atomicAdd(&cnt[ei[E+i]], 1);
}

__global__ void __launch_bounds__(256) k_dinv(const int* __restrict__ cnt, float* __restrict__ dinv, int N){
  int i = blockIdx.x*blockDim.x + threadIdx.x;
  if (i < N) dinv[i] = rsqrtf((float)(cnt[i]+1));
}

// ---- exclusive scan (3-phase) ----
__global__ void __launch_bounds__(256) k_scan1(const int* __restrict__ cnt, int* __restrict__ offs,
                                               int* __restrict__ bsum, int N){
  __shared__ int s[256];
  int t=threadIdx.x, gid=blockIdx.x*256+t;
  int v = (gid<N)? cnt[gid] : 0;
  s[t]=v; __syncthreads();
  for (int o=1;o<256;o<<=1){ int x=(t>=o)?s[t-o]:0; __syncthreads(); s[t]+=x; __syncthreads(); }
  if (gid<N) offs[gid]=s[t]-v;
  if (t==255) bsum[blockIdx.x]=s[t];
}

__global__ void __launch_bounds__(512) k_scan2(int* __restrict__ bsum, int nb){
  __shared__ int s[512];
  int t=threadIdx.x;
  int v=(t<nb)?bsum[t]:0; s[t]=v; __syncthreads();
  for(int o=1;o<512;o<<=1){ int x=(t>=o)?s[t-o]:0; __syncthreads(); s[t]+=x; __syncthreads(); }
  if (t<nb) bsum[t]=s[t]-v;
}

__global__ void __launch_bounds__(256) k_scan3(int* __restrict__ offs, const int* __restrict__ bsum,
                                               int* __restrict__ cur, int N, int E){
  int gid=blockIdx.x*256+threadIdx.x;
  if (gid<N){ int o=offs[gid]+bsum[gid>>8]; offs[gid]=o; cur[gid]=o; }
  if (gid==0) offs[N]=E;
}

// ---- CSR fill (sorted by col) ----
__global__ void __launch_bounds__(256) k_fill(const int* __restrict__ ei, int E,
                                              int* __restrict__ cur, int* __restrict__ esrc){
  int i = blockIdx.x*blockDim.x + threadIdx.x;
  int stride = gridDim.x*blockDim.x;
  for (; i<E; i+=stride){
    int r = ei[i], c = ei[E+i];
    int pos = atomicAdd(&cur[c],1);
    esrc[pos]=r;
  }
}

// ---- x -> bf16 into X[:, 0:512] ----
__global__ void __launch_bounds__(256) k_xcast(const float* __restrict__ x, unsigned short* __restrict__ X, int N){
  int i = blockIdx.x*blockDim.x + threadIdx.x; // one thread per 4 floats
  int total = N*(FF/4);
  if (i >= total) return;
  int row = i/(FF/4), c4 = (i%(FF/4))*4;
  float4 v = *(const float4*)(x + (size_t)row*FF + c4);
  ushort4 o; o.x=f2bf(v.x); o.y=f2bf(v.y); o.z=f2bf(v.z); o.w=f2bf(v.w);
  *(ushort4*)(X + (size_t)row*XDIM + c4) = o;
}

// ---- W (fp32 [d][ncols]) -> bf16 MFMA B-fragment layout [kb][nt][lane][8] ----
__global__ void __launch_bounds__(256) k_wfrag(const float* __restrict__ W, unsigned short* __restrict__ dst,
                                               int d, int ntile, int ncols){
  int idx = blockIdx.x*blockDim.x + threadIdx.x;
  int total = (d>>5)*ntile*512;
  if (idx>=total) return;
  int j = idx&7, lane=(idx>>3)&63, rem=idx>>9;
  int nt = rem % ntile, kb = rem / ntile;
  int k = kb*32 + (lane>>4)*8 + j;
  int c = nt*16 + (lane&15);
  float v = (c<ncols)? W[(size_t)k*ncols + c] : 0.f;
  dst[idx]=f2bf(v);
}

// ---- lin[N,64] = (X[:, :32*nkb] @ Wf) * dinv[row] ; 4 waves/block, 16 rows/wave ----
__global__ void __launch_bounds__(256) k_gemm(const unsigned short* __restrict__ X,
                                              const unsigned short* __restrict__ Wf,
                                              const float* __restrict__ dinv,
                                              unsigned short* __restrict__ lin,
                                              int N, int nkb){
  int lane = threadIdx.x & 63, wid = threadIdx.x >> 6;
  long row0 = (long)blockIdx.x*64 + wid*16;
  int arow = lane & 15, kgrp = lane >> 4;
  long r = row0 + arow; if (r > (long)N-1) r = N-1;
  const unsigned short* aptr = X + (size_t)r*XDIM + kgrp*8;
  const unsigned short* bptr = Wf + lane*8;
  f32x4 acc0 = {0.f,0.f,0.f,0.f}, acc1 = acc0, acc2 = acc0, acc3 = acc0;
  for (int kb=0; kb<nkb; ++kb){
    bf16x8 a = *(const bf16x8*)(aptr + (size_t)kb*32);
    const unsigned short* bp = bptr + (size_t)kb*2048;
    bf16x8 b0=*(const bf16x8*)bp, b1=*(const bf16x8*)(bp+512),
           b2=*(const bf16x8*)(bp+1024), b3=*(const bf16x8*)(bp+1536);
    acc0=__builtin_amdgcn_mfma_f32_16x16x32_bf16(a,b0,acc0,0,0,0);
    acc1=__builtin_amdgcn_mfma_f32_16x16x32_bf16(a,b1,acc1,0,0,0);
    acc2=__builtin_amdgcn_mfma_f32_16x16x32_bf16(a,b2,acc2,0,0,0);
    acc3=__builtin_amdgcn_mfma_f32_16x16x32_bf16(a,b3,acc3,0,0,0);
  }
  // D: col = lane&15, row = (lane>>4)*4 + reg; scale by dinv[row]
  for (int j=0;j<4;++j){
    long rr = row0 + kgrp*4 + j;
    if (rr < N){
      float dv = dinv[rr];
      unsigned short* lp = lin + (size_t)rr*64 + arow;
      lp[0]  = f2bf(acc0[j]*dv);
      lp[16] = f2bf(acc1[j]*dv);
      lp[32] = f2bf(acc2[j]*dv);
      lp[48] = f2bf(acc3[j]*dv);
    }
  }
}

// ---- aggregate: 1 wave per node, lane = feature; linS already scaled by dinv[src] ----
__global__ void __launch_bounds__(256) k_agg(const unsigned short* __restrict__ lin,
                                             const int* __restrict__ offs,
                                             const int* __restrict__ esrc,
                                             const float* __restrict__ dinv,
                                             const float* __restrict__ bias,
                                             unsigned short* __restrict__ X,
                                             int colbase, int N){
  int lane = threadIdx.x & 63, wid = threadIdx.x >> 6;
  int n = blockIdx.x*4 + wid;
  if (n >= N) return;
  float acc = bf2f(lin[(size_t)n*64 + lane]);   // self-loop: dinv*lin, *dinv again below
  int s = offs[n], e = offs[n+1];
  for (int base = s; base < e; base += 64){
    int cnt = e - base; if (cnt > 64) cnt = 64;
    int srcv = (base + lane < e) ? esrc[base + lane] : 0;
    int cnt4 = cnt & ~3;
    int j = 0;
    for (; j < cnt4; j += 4){
      int s0 = __builtin_amdgcn_readlane(srcv, j+0);
      int s1 = __builtin_amdgcn_readlane(srcv, j+1);
      int s2 = __builtin_amdgcn_readlane(srcv, j+2);
      int s3 = __builtin_amdgcn_readlane(srcv, j+3);
      float v0 = bf2f(lin[(size_t)s0*64 + lane]);
      float v1 = bf2f(lin[(size_t)s1*64 + lane]);
      float v2 = bf2f(lin[(size_t)s2*64 + lane]);
      float v3 = bf2f(lin[(size_t)s3*64 + lane]);
      acc += v0; acc += v1; acc += v2; acc += v3;
    }
    for (; j < cnt; ++j){
      int s0 = __builtin_amdgcn_readlane(srcv, j);
      acc += bf2f(lin[(size_t)s0*64 + lane]);
    }
  }
  float h = fmaxf(acc*dinv[n] + bias[lane], 0.f);
  X[(size_t)n*XDIM + colbase + lane] = f2bf(h);
}

// ---- final: logits = X @ Wlin + blin, log_softmax, write fp32 [N,40] ----
__global__ void __launch_bounds__(256) k_final(const unsigned short* __restrict__ X,
                                               const unsigned short* __restrict__ Wf,
                                               const float* __restrict__ blin,
                                               float* __restrict__ out, int N){
  int lane=threadIdx.x&63, wid=threadIdx.x>>6;
  long row0=(long)blockIdx.x*64 + wid*16;
  int c0=lane&15, g=lane>>4;
  long r=row0+c0; if (r > (long)N-1) r = N-1;
  const unsigned short* aptr = X + (size_t)r*XDIM + g*8;
  const unsigned short* bptr = Wf + lane*8;
  f32x4 acc0={0.f,0.f,0.f,0.f}, acc1=acc0, acc2=acc0;
  const int nkb = XDIM/32; // 28
  for (int kb=0;kb<nkb;++kb){
    bf16x8 a=*(const bf16x8*)(aptr+(size_t)kb*32);
    const unsigned short* bp = bptr + (size_t)kb*1536;
    bf16x8 b0=*(const bf16x8*)bp, b1=*(const bf16x8*)(bp+512), b2=*(const bf16x8*)(bp+1024);
    acc0=__builtin_amdgcn_mfma_f32_16x16x32_bf16(a,b0,acc0,0,0,0);
    acc1=__builtin_amdgcn_mfma_f32_16x16x32_bf16(a,b1,acc1,0,0,0);
    acc2=__builtin_amdgcn_mfma_f32_16x16x32_bf16(a,b2,acc2,0,0,0);
  }
  float bl0 = blin[c0], bl1 = blin[16+c0];
  bool v2ok = (c0 < 8);
  float bl2 = v2ok ? blin[32+c0] : 0.f;
  for (int j=0;j<4;++j){
    long rr = row0 + g*4 + j;
    float v0 = acc0[j]+bl0, v1 = acc1[j]+bl1;
    float v2 = v2ok ? (acc2[j]+bl2) : -1e30f;
    float m = fmaxf(fmaxf(v0,v1),v2);
    m = fmaxf(m, __shfl_xor(m,1,64));
    m = fmaxf(m, __shfl_xor(m,2,64));
    m = fmaxf(m, __shfl_xor(m,4,64));
    m = fmaxf(m, __shfl_xor(m,8,64));
    float sEx = expf(v0-m)+expf(v1-m)+(v2ok?expf(v2-m):0.f);
    sEx += __shfl_xor(sEx,1,64);
    sEx += __shfl_xor(sEx,2,64);
    sEx += __shfl_xor(sEx,4,64);
    sEx += __shfl_xor(sEx,8,64);
    float lse = m + logf(sEx);
    if (rr < N){
      out[(size_t)rr*CC + c0]      = v0 - lse;
      out[(size_t)rr*CC + 16 + c0] = v1 - lse;
      if (v2ok) out[(size_t)rr*CC + 32 + c0] = v2 - lse;
    }
  }
}

extern "C" void kernel_launch(void* const* d_in, const int* in_sizes, int n_in,
                              void* d_out, int out_size, void* d_ws, size_t ws_size,
                              hipStream_t stream){
  const float* x = (const float*)d_in[0];
  const int* ei = (const int*)d_in[1];
  const float* Wl[LL]; const float* bl[LL];
  for (int i=0;i<LL;i++){ Wl[i]=(const float*)d_in[2+2*i]; bl[i]=(const float*)d_in[3+2*i]; }
  const float* Wlin = (const float*)d_in[2+2*LL];
  const float* blin = (const float*)d_in[3+2*LL];
  float* out = (float*)d_out;
  const int N = in_sizes[0]/FF;
  const int E = in_sizes[1]/2;

  char* p = (char*)d_ws;
  auto alloc = [&](size_t b)->char*{ char* r=p; p += (b+255)&~(size_t)255; return r; };
  unsigned short* X   = (unsigned short*)alloc((size_t)N*XDIM*2);
  unsigned short* lin = (unsigned short*)alloc((size_t)N*64*2);
  unsigned short* WfL[LL];
  for (int i=0;i<LL;i++){ int d=FF+HH*i; WfL[i]=(unsigned short*)alloc((size_t)d*64*2); }
  unsigned short* WfLin = (unsigned short*)alloc((size_t)XDIM*48*2);
  float* dinv = (float*)alloc((size_t)N*4);
  int* cnt    = (int*)alloc((size_t)N*4);
  int* offs   = (int*)alloc((size_t)(N+1)*4);
  int* cur    = (int*)alloc((size_t)N*4);
  int* bsum   = (int*)alloc(512*4);
  int* esrc   = (int*)alloc((size_t)E*4);

  hipMemsetAsync(cnt, 0, (size_t)N*4, stream);

  int nb = (N+255)/256;
  k_count<<<2048, 256, 0, stream>>>(ei, E, cnt);
  k_dinv <<<nb, 256, 0, stream>>>(cnt, dinv, N);
  k_scan1<<<nb, 256, 0, stream>>>(cnt, offs, bsum, N);
  k_scan2<<<1, 512, 0, stream>>>(bsum, nb);
  k_scan3<<<nb, 256, 0, stream>>>(offs, bsum, cur, N, E);
  k_fill <<<2048, 256, 0, stream>>>(ei, E, cur, esrc);
  k_xcast<<<(N*(FF/4)+255)/256, 256, 0, stream>>>(x, X, N);
  for (int i=0;i<LL;i++){
    int d = FF+HH*i;
    int tot = (d>>5)*4*512;
    k_wfrag<<<(tot+255)/256,256,0,stream>>>(Wl[i], WfL[i], d, 4, HH);
  }
  { int tot = (XDIM>>5)*3*512;
    k_wfrag<<<(tot+255)/256,256,0,stream>>>(Wlin, WfLin, XDIM, 3, CC); }

  int gb = (N+63)/64;
  int ab = (N+3)/4;
  for (int i=0;i<LL;i++){
    k_gemm<<<gb,256,0,stream>>>(X, WfL[i], dinv, lin, N, (FF+HH*i)>>5);
    k_agg <<<ab,256,0,stream>>>(lin, offs, esrc, dinv, bl[i], X, FF+HH*i, N);
  }
  k_final<<<gb,256,0,stream>>>(X, WfLin, blin, out, N);
}

// Round 3
// 864.799 us; speedup vs baseline: 1.6281x; 1.0079x over previous
//
#include <hip/hip_runtime.h>
#include <hip/hip_bf16.h>

#define HH 64
#define XDIM 896
#define FF 512
#define LL 6
#define CC 40

typedef __bf16 bf16x8 __attribute__((ext_vector_type(8)));
typedef float f32x4 __attribute__((ext_vector_type(4)));

__device__ __forceinline__ float bf2f(unsigned short u){
  union{unsigned int u; float f;} v; v.u = ((unsigned int)u)<<16; return v.f;
}
__device__ __forceinline__ unsigned short f2bf(float f){
  union{float f; unsigned int u;} v; v.f=f; unsigned int u=v.u;
  return (unsigned short)((u + 0x7fffu + ((u>>16)&1u))>>16);
}

// ---- degree count ----
__global__ void __launch_bounds__(256) k_count(const int* __restrict__ ei, int E, int* __restrict__ cnt){
  int i = blockIdx.x*blockDim.x + threadIdx.x;
  int stride = gridDim.x*blockDim.x;
  for (; i < E; i += stride) atomicAdd(&cnt[ei[E+i]], 1);
}

__global__ void __launch_bounds__(256) k_dinv(const int* __restrict__ cnt, float* __restrict__ dinv, int N){
  int i = blockIdx.x*blockDim.x + threadIdx.x;
  if (i < N) dinv[i] = rsqrtf((float)(cnt[i]+1));
}

// ---- exclusive scan (3-phase) ----
__global__ void __launch_bounds__(256) k_scan1(const int* __restrict__ cnt, int* __restrict__ offs,
                                               int* __restrict__ bsum, int N){
  __shared__ int s[256];
  int t=threadIdx.x, gid=blockIdx.x*256+t;
  int v = (gid<N)? cnt[gid] : 0;
  s[t]=v; __syncthreads();
  for (int o=1;o<256;o<<=1){ int x=(t>=o)?s[t-o]:0; __syncthreads(); s[t]+=x; __syncthreads(); }
  if (gid<N) offs[gid]=s[t]-v;
  if (t==255) bsum[blockIdx.x]=s[t];
}

__global__ void __launch_bounds__(512) k_scan2(int* __restrict__ bsum, int nb){
  __shared__ int s[512];
  int t=threadIdx.x;
  int v=(t<nb)?bsum[t]:0; s[t]=v; __syncthreads();
  for(int o=1;o<512;o<<=1){ int x=(t>=o)?s[t-o]:0; __syncthreads(); s[t]+=x; __syncthreads(); }
  if (t<nb) bsum[t]=s[t]-v;
}

__global__ void __launch_bounds__(256) k_scan3(int* __restrict__ offs, const int* __restrict__ bsum,
                                               int* __restrict__ cur, int N, int E){
  int gid=blockIdx.x*256+threadIdx.x;
  if (gid<N){ int o=offs[gid]+bsum[gid>>8]; offs[gid]=o; cur[gid]=o; }
  if (gid==0) offs[N]=E;
}

// ---- bucket cursor init: bucket b = nodes [16b, 16b+16) ----
__global__ void __launch_bounds__(256) k_binit(const int* __restrict__ offs, int* __restrict__ bcur, int nbk){
  int b = blockIdx.x*blockDim.x + threadIdx.x;
  if (b < nbk) bcur[b] = offs[b*16];
}

// ---- pass B: bucket-partition edges; writes are sequential appends per bucket ----
__global__ void __launch_bounds__(256) k_bfill(const int* __restrict__ ei, int E,
                                               int* __restrict__ bcur, unsigned* __restrict__ tmp){
  int i = blockIdx.x*blockDim.x + threadIdx.x;
  int stride = gridDim.x*blockDim.x;
  for (; i<E; i+=stride){
    int r = ei[i], c = ei[E+i];
    int pos = atomicAdd(&bcur[c>>4], 1);
    tmp[pos] = ((unsigned)r<<4) | (unsigned)(c & 15);
  }
}

// ---- pass C: within-bucket scatter to node-level CSR (line-local writes) ----
__global__ void __launch_bounds__(256) k_scatter(const unsigned* __restrict__ tmp,
                                                 const int* __restrict__ offs,
                                                 int* __restrict__ cur, int* __restrict__ esrc, int N){
  int b = blockIdx.x;
  int n0 = b*16;
  int n1 = n0+16; if (n1 > N) n1 = N;
  int start = offs[n0], end = offs[n1];
  for (int i = start + threadIdx.x; i < end; i += 256){
    unsigned v = tmp[i];
    int c = n0 + (int)(v & 15u);
    int r = (int)(v >> 4);
    int pos = atomicAdd(&cur[c], 1);
    esrc[pos] = r;
  }
}

// ---- x -> bf16 into X[:, 0:512] ----
__global__ void __launch_bounds__(256) k_xcast(const float* __restrict__ x, unsigned short* __restrict__ X, int N){
  int i = blockIdx.x*blockDim.x + threadIdx.x; // one thread per 4 floats
  int total = N*(FF/4);
  if (i >= total) return;
  int row = i/(FF/4), c4 = (i%(FF/4))*4;
  float4 v = *(const float4*)(x + (size_t)row*FF + c4);
  ushort4 o; o.x=f2bf(v.x); o.y=f2bf(v.y); o.z=f2bf(v.z); o.w=f2bf(v.w);
  *(ushort4*)(X + (size_t)row*XDIM + c4) = o;
}

// ---- W (fp32 [d][ncols]) -> bf16 MFMA B-fragment layout [kb][nt][lane][8] ----
__global__ void __launch_bounds__(256) k_wfrag(const float* __restrict__ W, unsigned short* __restrict__ dst,
                                               int d, int ntile, int ncols){
  int idx = blockIdx.x*blockDim.x + threadIdx.x;
  int total = (d>>5)*ntile*512;
  if (idx>=total) return;
  int j = idx&7, lane=(idx>>3)&63, rem=idx>>9;
  int nt = rem % ntile, kb = rem / ntile;
  int k = kb*32 + (lane>>4)*8 + j;
  int c = nt*16 + (lane&15);
  float v = (c<ncols)? W[(size_t)k*ncols + c] : 0.f;
  dst[idx]=f2bf(v);
}

// ---- lin[N,64] = (X[:, :32*nkb] @ Wf) * dinv[row] ; 4 waves/block, 16 rows/wave ----
__global__ void __launch_bounds__(256) k_gemm(const unsigned short* __restrict__ X,
                                              const unsigned short* __restrict__ Wf,
                                              const float* __restrict__ dinv,
                                              unsigned short* __restrict__ lin,
                                              int N, int nkb){
  int lane = threadIdx.x & 63, wid = threadIdx.x >> 6;
  long row0 = (long)blockIdx.x*64 + wid*16;
  int arow = lane & 15, kgrp = lane >> 4;
  long r = row0 + arow; if (r > (long)N-1) r = N-1;
  const unsigned short* aptr = X + (size_t)r*XDIM + kgrp*8;
  const unsigned short* bptr = Wf + lane*8;
  f32x4 acc0 = {0.f,0.f,0.f,0.f}, acc1 = acc0, acc2 = acc0, acc3 = acc0;
  for (int kb=0; kb<nkb; ++kb){
    bf16x8 a = *(const bf16x8*)(aptr + (size_t)kb*32);
    const unsigned short* bp = bptr + (size_t)kb*2048;
    bf16x8 b0=*(const bf16x8*)bp, b1=*(const bf16x8*)(bp+512),
           b2=*(const bf16x8*)(bp+1024), b3=*(const bf16x8*)(bp+1536);
    acc0=__builtin_amdgcn_mfma_f32_16x16x32_bf16(a,b0,acc0,0,0,0);
    acc1=__builtin_amdgcn_mfma_f32_16x16x32_bf16(a,b1,acc1,0,0,0);
    acc2=__builtin_amdgcn_mfma_f32_16x16x32_bf16(a,b2,acc2,0,0,0);
    acc3=__builtin_amdgcn_mfma_f32_16x16x32_bf16(a,b3,acc3,0,0,0);
  }
  // D: col = lane&15, row = (lane>>4)*4 + reg; scale by dinv[row]
  for (int j=0;j<4;++j){
    long rr = row0 + kgrp*4 + j;
    if (rr < N){
      float dv = dinv[rr];
      unsigned short* lp = lin + (size_t)rr*64 + arow;
      lp[0]  = f2bf(acc0[j]*dv);
      lp[16] = f2bf(acc1[j]*dv);
      lp[32] = f2bf(acc2[j]*dv);
      lp[48] = f2bf(acc3[j]*dv);
    }
  }
}

// ---- aggregate: 1 wave per node, lane = feature; lin already scaled by dinv[src] ----
__global__ void __launch_bounds__(256) k_agg(const unsigned short* __restrict__ lin,
                                             const int* __restrict__ offs,
                                             const int* __restrict__ esrc,
                                             const float* __restrict__ dinv,
                                             const float* __restrict__ bias,
                                             unsigned short* __restrict__ X,
                                             int colbase, int N){
  int lane = threadIdx.x & 63, wid = threadIdx.x >> 6;
  int n = blockIdx.x*4 + wid;
  if (n >= N) return;
  float acc = bf2f(lin[(size_t)n*64 + lane]);   // self-loop contribution
  int s = offs[n], e = offs[n+1];
  for (int base = s; base < e; base += 64){
    int cnt = e - base; if (cnt > 64) cnt = 64;
    int srcv = (base + lane < e) ? esrc[base + lane] : 0;
    int j = 0;
    int cnt8 = cnt & ~7;
    for (; j < cnt8; j += 8){
      int s0 = __builtin_amdgcn_readlane(srcv, j+0);
      int s1 = __builtin_amdgcn_readlane(srcv, j+1);
      int s2 = __builtin_amdgcn_readlane(srcv, j+2);
      int s3 = __builtin_amdgcn_readlane(srcv, j+3);
      int s4 = __builtin_amdgcn_readlane(srcv, j+4);
      int s5 = __builtin_amdgcn_readlane(srcv, j+5);
      int s6 = __builtin_amdgcn_readlane(srcv, j+6);
      int s7 = __builtin_amdgcn_readlane(srcv, j+7);
      float v0 = bf2f(lin[(size_t)s0*64 + lane]);
      float v1 = bf2f(lin[(size_t)s1*64 + lane]);
      float v2 = bf2f(lin[(size_t)s2*64 + lane]);
      float v3 = bf2f(lin[(size_t)s3*64 + lane]);
      float v4 = bf2f(lin[(size_t)s4*64 + lane]);
      float v5 = bf2f(lin[(size_t)s5*64 + lane]);
      float v6 = bf2f(lin[(size_t)s6*64 + lane]);
      float v7 = bf2f(lin[(size_t)s7*64 + lane]);
      acc += v0; acc += v1; acc += v2; acc += v3;
      acc += v4; acc += v5; acc += v6; acc += v7;
    }
    for (; j < cnt; ++j){
      int s0 = __builtin_amdgcn_readlane(srcv, j);
      acc += bf2f(lin[(size_t)s0*64 + lane]);
    }
  }
  float h = fmaxf(acc*dinv[n] + bias[lane], 0.f);
  X[(size_t)n*XDIM + colbase + lane] = f2bf(h);
}

// ---- final: logits = X @ Wlin + blin, log_softmax, write fp32 [N,40] ----
__global__ void __launch_bounds__(256) k_final(const unsigned short* __restrict__ X,
                                               const unsigned short* __restrict__ Wf,
                                               const float* __restrict__ blin,
                                               float* __restrict__ out, int N){
  int lane=threadIdx.x&63, wid=threadIdx.x>>6;
  long row0=(long)blockIdx.x*64 + wid*16;
  int c0=lane&15, g=lane>>4;
  long r=row0+c0; if (r > (long)N-1) r = N-1;
  const unsigned short* aptr = X + (size_t)r*XDIM + g*8;
  const unsigned short* bptr = Wf + lane*8;
  f32x4 acc0={0.f,0.f,0.f,0.f}, acc1=acc0, acc2=acc0;
  const int nkb = XDIM/32; // 28
  for (int kb=0;kb<nkb;++kb){
    bf16x8 a=*(const bf16x8*)(aptr+(size_t)kb*32);
    const unsigned short* bp = bptr + (size_t)kb*1536;
    bf16x8 b0=*(const bf16x8*)bp, b1=*(const bf16x8*)(bp+512), b2=*(const bf16x8*)(bp+1024);
    acc0=__builtin_amdgcn_mfma_f32_16x16x32_bf16(a,b0,acc0,0,0,0);
    acc1=__builtin_amdgcn_mfma_f32_16x16x32_bf16(a,b1,acc1,0,0,0);
    acc2=__builtin_amdgcn_mfma_f32_16x16x32_bf16(a,b2,acc2,0,0,0);
  }
  float bl0 = blin[c0], bl1 = blin[16+c0];
  bool v2ok = (c0 < 8);
  float bl2 = v2ok ? blin[32+c0] : 0.f;
  for (int j=0;j<4;++j){
    long rr = row0 + g*4 + j;
    float v0 = acc0[j]+bl0, v1 = acc1[j]+bl1;
    float v2 = v2ok ? (acc2[j]+bl2) : -1e30f;
    float m = fmaxf(fmaxf(v0,v1),v2);
    m = fmaxf(m, __shfl_xor(m,1,64));
    m = fmaxf(m, __shfl_xor(m,2,64));
    m = fmaxf(m, __shfl_xor(m,4,64));
    m = fmaxf(m, __shfl_xor(m,8,64));
    float sEx = expf(v0-m)+expf(v1-m)+(v2ok?expf(v2-m):0.f);
    sEx += __shfl_xor(sEx,1,64);
    sEx += __shfl_xor(sEx,2,64);
    sEx += __shfl_xor(sEx,4,64);
    sEx += __shfl_xor(sEx,8,64);
    float lse = m + logf(sEx);
    if (rr < N){
      out[(size_t)rr*CC + c0]      = v0 - lse;
      out[(size_t)rr*CC + 16 + c0] = v1 - lse;
      if (v2ok) out[(size_t)rr*CC + 32 + c0] = v2 - lse;
    }
  }
}

extern "C" void kernel_launch(void* const* d_in, const int* in_sizes, int n_in,
                              void* d_out, int out_size, void* d_ws, size_t ws_size,
                              hipStream_t stream){
  const float* x = (const float*)d_in[0];
  const int* ei = (const int*)d_in[1];
  const float* Wl[LL]; const float* bl[LL];
  for (int i=0;i<LL;i++){ Wl[i]=(const float*)d_in[2+2*i]; bl[i]=(const float*)d_in[3+2*i]; }
  const float* Wlin = (const float*)d_in[2+2*LL];
  const float* blin = (const float*)d_in[3+2*LL];
  float* out = (float*)d_out;
  const int N = in_sizes[0]/FF;
  const int E = in_sizes[1]/2;
  const int nbk = (N+15)/16;

  char* p = (char*)d_ws;
  auto alloc = [&](size_t b)->char*{ char* r=p; p += (b+255)&~(size_t)255; return r; };
  unsigned short* X   = (unsigned short*)alloc((size_t)N*XDIM*2);
  unsigned short* lin = (unsigned short*)alloc((size_t)N*64*2);
  unsigned* tmp = (unsigned*)lin;  // alias: tmp (E*4B = 6.4MB) used only before GEMM phase
  unsigned short* WfL[LL];
  for (int i=0;i<LL;i++){ int d=FF+HH*i; WfL[i]=(unsigned short*)alloc((size_t)d*64*2); }
  unsigned short* WfLin = (unsigned short*)alloc((size_t)XDIM*48*2);
  float* dinv = (float*)alloc((size_t)N*4);
  int* cnt    = (int*)alloc((size_t)N*4);
  int* offs   = (int*)alloc((size_t)(N+1)*4);
  int* cur    = (int*)alloc((size_t)N*4);
  int* bcur   = (int*)alloc((size_t)nbk*4);
  int* bsum   = (int*)alloc(512*4);
  int* esrc   = (int*)alloc((size_t)E*4);

  hipMemsetAsync(cnt, 0, (size_t)N*4, stream);

  int nb = (N+255)/256;
  k_count<<<2048, 256, 0, stream>>>(ei, E, cnt);
  k_dinv <<<nb, 256, 0, stream>>>(cnt, dinv, N);
  k_scan1<<<nb, 256, 0, stream>>>(cnt, offs, bsum, N);
  k_scan2<<<1, 512, 0, stream>>>(bsum, nb);
  k_scan3<<<nb, 256, 0, stream>>>(offs, bsum, cur, N, E);
  k_binit<<<(nbk+255)/256, 256, 0, stream>>>(offs, bcur, nbk);
  k_bfill<<<2048, 256, 0, stream>>>(ei, E, bcur, tmp);
  k_scatter<<<nbk, 256, 0, stream>>>(tmp, offs, cur, esrc, N);
  k_xcast<<<(N*(FF/4)+255)/256, 256, 0, stream>>>(x, X, N);
  for (int i=0;i<LL;i++){
    int d = FF+HH*i;
    int tot = (d>>5)*4*512;
    k_wfrag<<<(tot+255)/256,256,0,stream>>>(Wl[i], WfL[i], d, 4, HH);
  }
  { int tot = (XDIM>>5)*3*512;
    k_wfrag<<<(tot+255)/256,256,0,stream>>>(Wlin, WfLin, XDIM, 3, CC); }

  int gb = (N+63)/64;
  int ab = (N+3)/4;
  for (int i=0;i<LL;i++){
    k_gemm<<<gb,256,0,stream>>>(X, WfL[i], dinv, lin, N, (FF+HH*i)>>5);
    k_agg <<<ab,256,0,stream>>>(lin, offs, esrc, dinv, bl[i], X, FF+HH*i, N);
  }
  k_final<<<gb,256,0,stream>>>(X, WfLin, blin, out, N);
}

// Round 4
// 781.844 us; speedup vs baseline: 1.8008x; 1.1061x over previous
//
#include <hip/hip_runtime.h>
#include <hip/hip_bf16.h>

#define HH 64
#define XDIM 896
#define FF 512
#define LL 6
#define CC 40

typedef __bf16 bf16x8 __attribute__((ext_vector_type(8)));
typedef float f32x4 __attribute__((ext_vector_type(4)));

__device__ __forceinline__ float bf2f(unsigned short u){
  union{unsigned int u; float f;} v; v.u = ((unsigned int)u)<<16; return v.f;
}
__device__ __forceinline__ unsigned short f2bf(float f){
  union{float f; unsigned int u;} v; v.f=f; unsigned int u=v.u;
  return (unsigned short)((u + 0x7fffu + ((u>>16)&1u))>>16);
}
__device__ __forceinline__ float u2f(unsigned u){
  union{unsigned u; float f;} v; v.u=u; return v.f;
}

// ---- degree count ----
__global__ void __launch_bounds__(256) k_count(const int* __restrict__ ei, int E, int* __restrict__ cnt){
  int i = blockIdx.x*blockDim.x + threadIdx.x;
  int stride = gridDim.x*blockDim.x;
  for (; i < E; i += stride) atomicAdd(&cnt[ei[E+i]], 1);
}

__global__ void __launch_bounds__(256) k_dinv(const int* __restrict__ cnt, float* __restrict__ dinv, int N){
  int i = blockIdx.x*blockDim.x + threadIdx.x;
  if (i < N) dinv[i] = rsqrtf((float)(cnt[i]+1));
}

// ---- exclusive scan (3-phase) ----
__global__ void __launch_bounds__(256) k_scan1(const int* __restrict__ cnt, int* __restrict__ offs,
                                               int* __restrict__ bsum, int N){
  __shared__ int s[256];
  int t=threadIdx.x, gid=blockIdx.x*256+t;
  int v = (gid<N)? cnt[gid] : 0;
  s[t]=v; __syncthreads();
  for (int o=1;o<256;o<<=1){ int x=(t>=o)?s[t-o]:0; __syncthreads(); s[t]+=x; __syncthreads(); }
  if (gid<N) offs[gid]=s[t]-v;
  if (t==255) bsum[blockIdx.x]=s[t];
}

__global__ void __launch_bounds__(512) k_scan2(int* __restrict__ bsum, int nb){
  __shared__ int s[512];
  int t=threadIdx.x;
  int v=(t<nb)?bsum[t]:0; s[t]=v; __syncthreads();
  for(int o=1;o<512;o<<=1){ int x=(t>=o)?s[t-o]:0; __syncthreads(); s[t]+=x; __syncthreads(); }
  if (t<nb) bsum[t]=s[t]-v;
}

__global__ void __launch_bounds__(256) k_scan3(int* __restrict__ offs, const int* __restrict__ bsum,
                                               int N, int E){
  int gid=blockIdx.x*256+threadIdx.x;
  if (gid<N){ int o=offs[gid]+bsum[gid>>8]; offs[gid]=o; }
  if (gid==0) offs[N]=E;
}

// ---- bucket cursor init: bucket b = nodes [16b, 16b+16) ----
__global__ void __launch_bounds__(256) k_binit(const int* __restrict__ offs, int* __restrict__ bcur, int nbk){
  int b = blockIdx.x*blockDim.x + threadIdx.x;
  if (b < nbk) bcur[b] = offs[b*16];
}

// ---- pass B: bucket-partition edges ----
__global__ void __launch_bounds__(256) k_bfill(const int* __restrict__ ei, int E,
                                               int* __restrict__ bcur, unsigned* __restrict__ tmp){
  int i = blockIdx.x*blockDim.x + threadIdx.x;
  int stride = gridDim.x*blockDim.x;
  for (; i<E; i+=stride){
    int r = ei[i], c = ei[E+i];
    int pos = atomicAdd(&bcur[c>>4], 1);
    tmp[pos] = ((unsigned)r<<4) | (unsigned)(c & 15);
  }
}

// ---- pass C: within-bucket scatter, LDS cursors (block owns its bucket) ----
__global__ void __launch_bounds__(256) k_scatter(const unsigned* __restrict__ tmp,
                                                 const int* __restrict__ offs,
                                                 int* __restrict__ esrc, int N){
  __shared__ int cur[16];
  int b = blockIdx.x;
  int n0 = b*16;
  int n1 = n0+16; if (n1 > N) n1 = N;
  if (threadIdx.x < 16 && n0 + threadIdx.x < n1)
    cur[threadIdx.x] = offs[n0 + threadIdx.x];
  __syncthreads();
  int start = offs[n0], end = offs[n1];
  for (int i = start + threadIdx.x; i < end; i += 256){
    unsigned v = tmp[i];
    int c = (int)(v & 15u);
    int r = (int)(v >> 4);
    int pos = atomicAdd(&cur[c], 1);
    esrc[pos] = r;
  }
}

// ---- x -> bf16 into X[:, 0:512] ----
__global__ void __launch_bounds__(256) k_xcast(const float* __restrict__ x, unsigned short* __restrict__ X, int N){
  int i = blockIdx.x*blockDim.x + threadIdx.x; // one thread per 4 floats
  int total = N*(FF/4);
  if (i >= total) return;
  int row = i/(FF/4), c4 = (i%(FF/4))*4;
  float4 v = *(const float4*)(x + (size_t)row*FF + c4);
  ushort4 o; o.x=f2bf(v.x); o.y=f2bf(v.y); o.z=f2bf(v.z); o.w=f2bf(v.w);
  *(ushort4*)(X + (size_t)row*XDIM + c4) = o;
}

// ---- W (fp32 [d][ncols]) -> bf16 MFMA B-fragment layout [kb][nt][lane][8] ----
__global__ void __launch_bounds__(256) k_wfrag(const float* __restrict__ W, unsigned short* __restrict__ dst,
                                               int d, int ntile, int ncols){
  int idx = blockIdx.x*blockDim.x + threadIdx.x;
  int total = (d>>5)*ntile*512;
  if (idx>=total) return;
  int j = idx&7, lane=(idx>>3)&63, rem=idx>>9;
  int nt = rem % ntile, kb = rem / ntile;
  int k = kb*32 + (lane>>4)*8 + j;
  int c = nt*16 + (lane&15);
  float v = (c<ncols)? W[(size_t)k*ncols + c] : 0.f;
  dst[idx]=f2bf(v);
}

// ---- lin[N,64] = (X[:, :32*nkb] @ Wf) * dinv[row] ; 4 waves/block, 16 rows/wave ----
__global__ void __launch_bounds__(256) k_gemm(const unsigned short* __restrict__ X,
                                              const unsigned short* __restrict__ Wf,
                                              const float* __restrict__ dinv,
                                              unsigned short* __restrict__ lin,
                                              int N, int nkb){
  int lane = threadIdx.x & 63, wid = threadIdx.x >> 6;
  long row0 = (long)blockIdx.x*64 + wid*16;
  int arow = lane & 15, kgrp = lane >> 4;
  long r = row0 + arow; if (r > (long)N-1) r = N-1;
  const unsigned short* aptr = X + (size_t)r*XDIM + kgrp*8;
  const unsigned short* bptr = Wf + lane*8;
  f32x4 acc0 = {0.f,0.f,0.f,0.f}, acc1 = acc0, acc2 = acc0, acc3 = acc0;
  for (int kb=0; kb<nkb; ++kb){
    bf16x8 a = *(const bf16x8*)(aptr + (size_t)kb*32);
    const unsigned short* bp = bptr + (size_t)kb*2048;
    bf16x8 b0=*(const bf16x8*)bp, b1=*(const bf16x8*)(bp+512),
           b2=*(const bf16x8*)(bp+1024), b3=*(const bf16x8*)(bp+1536);
    acc0=__builtin_amdgcn_mfma_f32_16x16x32_bf16(a,b0,acc0,0,0,0);
    acc1=__builtin_amdgcn_mfma_f32_16x16x32_bf16(a,b1,acc1,0,0,0);
    acc2=__builtin_amdgcn_mfma_f32_16x16x32_bf16(a,b2,acc2,0,0,0);
    acc3=__builtin_amdgcn_mfma_f32_16x16x32_bf16(a,b3,acc3,0,0,0);
  }
  // D: col = lane&15, row = (lane>>4)*4 + reg; scale by dinv[row]
  for (int j=0;j<4;++j){
    long rr = row0 + kgrp*4 + j;
    if (rr < N){
      float dv = dinv[rr];
      unsigned short* lp = lin + (size_t)rr*64 + arow;
      lp[0]  = f2bf(acc0[j]*dv);
      lp[16] = f2bf(acc1[j]*dv);
      lp[32] = f2bf(acc2[j]*dv);
      lp[48] = f2bf(acc3[j]*dv);
    }
  }
}

// ---- aggregate: 1 wave/node; lane = (sub=edge-slot, fq=feature-quad) ----
// 4 edges per dwordx2 gather; tail edges redirected to zero row lin[N].
__global__ void __launch_bounds__(256) k_agg(const unsigned short* __restrict__ lin,
                                             const int* __restrict__ offs,
                                             const int* __restrict__ esrc,
                                             const float* __restrict__ dinv,
                                             const float* __restrict__ bias,
                                             unsigned short* __restrict__ X,
                                             int colbase, int N){
  int lane = threadIdx.x & 63, wid = threadIdx.x >> 6;
  int n = blockIdx.x*4 + wid;
  if (n >= N) return;
  int sub = lane >> 4;           // edge slot within quad
  int fq  = lane & 15;           // feature quad: features 4fq..4fq+3
  int sub4 = sub*4;
  const unsigned short* lq = lin + fq*4;
  float a0=0.f, a1=0.f, a2=0.f, a3=0.f;
  int s = offs[n], e = offs[n+1];
  for (int base = s; base < e; base += 64){
    int cnt = e - base; if (cnt > 64) cnt = 64;
    int srcv = (base + lane < e) ? esrc[base + lane] : (int)N;
    int full = cnt & ~3;
    int j = 0;
    for (; j + 16 <= full; j += 16){
      int s0 = __builtin_amdgcn_ds_bpermute((j   )*4 + sub4, srcv);
      int s1 = __builtin_amdgcn_ds_bpermute((j+4 )*4 + sub4, srcv);
      int s2 = __builtin_amdgcn_ds_bpermute((j+8 )*4 + sub4, srcv);
      int s3 = __builtin_amdgcn_ds_bpermute((j+12)*4 + sub4, srcv);
      uint2 v0 = *(const uint2*)(lq + (size_t)s0*64);
      uint2 v1 = *(const uint2*)(lq + (size_t)s1*64);
      uint2 v2 = *(const uint2*)(lq + (size_t)s2*64);
      uint2 v3 = *(const uint2*)(lq + (size_t)s3*64);
      a0 += u2f(v0.x<<16); a1 += u2f(v0.x&0xffff0000u);
      a2 += u2f(v0.y<<16); a3 += u2f(v0.y&0xffff0000u);
      a0 += u2f(v1.x<<16); a1 += u2f(v1.x&0xffff0000u);
      a2 += u2f(v1.y<<16); a3 += u2f(v1.y&0xffff0000u);
      a0 += u2f(v2.x<<16); a1 += u2f(v2.x&0xffff0000u);
      a2 += u2f(v2.y<<16); a3 += u2f(v2.y&0xffff0000u);
      a0 += u2f(v3.x<<16); a1 += u2f(v3.x&0xffff0000u);
      a2 += u2f(v3.y<<16); a3 += u2f(v3.y&0xffff0000u);
    }
    for (; j < cnt; j += 4){
      int sx = __builtin_amdgcn_ds_bpermute(j*4 + sub4, srcv);
      sx = (j + sub < cnt) ? sx : (int)N;   // zero row for invalid slots
      uint2 v = *(const uint2*)(lq + (size_t)sx*64);
      a0 += u2f(v.x<<16); a1 += u2f(v.x&0xffff0000u);
      a2 += u2f(v.y<<16); a3 += u2f(v.y&0xffff0000u);
    }
  }
  // reduce across the 4 edge slots (bits 4,5 of lane)
  a0 += __shfl_xor(a0,16,64); a0 += __shfl_xor(a0,32,64);
  a1 += __shfl_xor(a1,16,64); a1 += __shfl_xor(a1,32,64);
  a2 += __shfl_xor(a2,16,64); a2 += __shfl_xor(a2,32,64);
  a3 += __shfl_xor(a3,16,64); a3 += __shfl_xor(a3,32,64);
  // self-loop (added once, after reduction)
  uint2 vs = *(const uint2*)(lq + (size_t)n*64);
  a0 += u2f(vs.x<<16); a1 += u2f(vs.x&0xffff0000u);
  a2 += u2f(vs.y<<16); a3 += u2f(vs.y&0xffff0000u);
  float dv = dinv[n];
  float4 b4 = *(const float4*)(bias + fq*4);
  float h0 = fmaxf(a0*dv + b4.x, 0.f);
  float h1 = fmaxf(a1*dv + b4.y, 0.f);
  float h2 = fmaxf(a2*dv + b4.z, 0.f);
  float h3 = fmaxf(a3*dv + b4.w, 0.f);
  if (sub == 0){
    ushort4 o; o.x=f2bf(h0); o.y=f2bf(h1); o.z=f2bf(h2); o.w=f2bf(h3);
    *(ushort4*)(X + (size_t)n*XDIM + colbase + fq*4) = o;
  }
}

// ---- final: logits = X @ Wlin + blin, log_softmax, write fp32 [N,40] ----
__global__ void __launch_bounds__(256) k_final(const unsigned short* __restrict__ X,
                                               const unsigned short* __restrict__ Wf,
                                               const float* __restrict__ blin,
                                               float* __restrict__ out, int N){
  int lane=threadIdx.x&63, wid=threadIdx.x>>6;
  long row0=(long)blockIdx.x*64 + wid*16;
  int c0=lane&15, g=lane>>4;
  long r=row0+c0; if (r > (long)N-1) r = N-1;
  const unsigned short* aptr = X + (size_t)r*XDIM + g*8;
  const unsigned short* bptr = Wf + lane*8;
  f32x4 acc0={0.f,0.f,0.f,0.f}, acc1=acc0, acc2=acc0;
  const int nkb = XDIM/32; // 28
  for (int kb=0;kb<nkb;++kb){
    bf16x8 a=*(const bf16x8*)(aptr+(size_t)kb*32);
    const unsigned short* bp = bptr + (size_t)kb*1536;
    bf16x8 b0=*(const bf16x8*)bp, b1=*(const bf16x8*)(bp+512), b2=*(const bf16x8*)(bp+1024);
    acc0=__builtin_amdgcn_mfma_f32_16x16x32_bf16(a,b0,acc0,0,0,0);
    acc1=__builtin_amdgcn_mfma_f32_16x16x32_bf16(a,b1,acc1,0,0,0);
    acc2=__builtin_amdgcn_mfma_f32_16x16x32_bf16(a,b2,acc2,0,0,0);
  }
  float bl0 = blin[c0], bl1 = blin[16+c0];
  bool v2ok = (c0 < 8);
  float bl2 = v2ok ? blin[32+c0] : 0.f;
  for (int j=0;j<4;++j){
    long rr = row0 + g*4 + j;
    float v0 = acc0[j]+bl0, v1 = acc1[j]+bl1;
    float v2 = v2ok ? (acc2[j]+bl2) : -1e30f;
    float m = fmaxf(fmaxf(v0,v1),v2);
    m = fmaxf(m, __shfl_xor(m,1,64));
    m = fmaxf(m, __shfl_xor(m,2,64));
    m = fmaxf(m, __shfl_xor(m,4,64));
    m = fmaxf(m, __shfl_xor(m,8,64));
    float sEx = expf(v0-m)+expf(v1-m)+(v2ok?expf(v2-m):0.f);
    sEx += __shfl_xor(sEx,1,64);
    sEx += __shfl_xor(sEx,2,64);
    sEx += __shfl_xor(sEx,4,64);
    sEx += __shfl_xor(sEx,8,64);
    float lse = m + logf(sEx);
    if (rr < N){
      out[(size_t)rr*CC + c0]      = v0 - lse;
      out[(size_t)rr*CC + 16 + c0] = v1 - lse;
      if (v2ok) out[(size_t)rr*CC + 32 + c0] = v2 - lse;
    }
  }
}

extern "C" void kernel_launch(void* const* d_in, const int* in_sizes, int n_in,
                              void* d_out, int out_size, void* d_ws, size_t ws_size,
                              hipStream_t stream){
  const float* x = (const float*)d_in[0];
  const int* ei = (const int*)d_in[1];
  const float* Wl[LL]; const float* bl[LL];
  for (int i=0;i<LL;i++){ Wl[i]=(const float*)d_in[2+2*i]; bl[i]=(const float*)d_in[3+2*i]; }
  const float* Wlin = (const float*)d_in[2+2*LL];
  const float* blin = (const float*)d_in[3+2*LL];
  float* out = (float*)d_out;
  const int N = in_sizes[0]/FF;
  const int E = in_sizes[1]/2;
  const int nbk = (N+15)/16;

  char* p = (char*)d_ws;
  auto alloc = [&](size_t b)->char*{ char* r=p; p += (b+255)&~(size_t)255; return r; };
  unsigned short* X   = (unsigned short*)alloc((size_t)N*XDIM*2);
  unsigned short* lin = (unsigned short*)alloc((size_t)(N+1)*64*2);  // +1 zero row
  unsigned* tmp = (unsigned*)lin;  // alias: tmp (E*4B) used only before GEMM phase
  unsigned short* WfL[LL];
  for (int i=0;i<LL;i++){ int d=FF+HH*i; WfL[i]=(unsigned short*)alloc((size_t)d*64*2); }
  unsigned short* WfLin = (unsigned short*)alloc((size_t)XDIM*48*2);
  float* dinv = (float*)alloc((size_t)N*4);
  int* cnt    = (int*)alloc((size_t)N*4);
  int* offs   = (int*)alloc((size_t)(N+1)*4);
  int* bcur   = (int*)alloc((size_t)nbk*4);
  int* bsum   = (int*)alloc(512*4);
  int* esrc   = (int*)alloc((size_t)E*4);

  hipMemsetAsync(cnt, 0, (size_t)N*4, stream);

  int nb = (N+255)/256;
  k_count<<<2048, 256, 0, stream>>>(ei, E, cnt);
  k_dinv <<<nb, 256, 0, stream>>>(cnt, dinv, N);
  k_scan1<<<nb, 256, 0, stream>>>(cnt, offs, bsum, N);
  k_scan2<<<1, 512, 0, stream>>>(bsum, nb);
  k_scan3<<<nb, 256, 0, stream>>>(offs, bsum, N, E);
  k_binit<<<(nbk+255)/256, 256, 0, stream>>>(offs, bcur, nbk);
  k_bfill<<<2048, 256, 0, stream>>>(ei, E, bcur, tmp);
  k_scatter<<<nbk, 256, 0, stream>>>(tmp, offs, esrc, N);
  k_xcast<<<(N*(FF/4)+255)/256, 256, 0, stream>>>(x, X, N);
  // zero row N of lin (tmp no longer needed; region beyond tmp anyway)
  hipMemsetAsync(lin + (size_t)N*64, 0, 128, stream);
  for (int i=0;i<LL;i++){
    int d = FF+HH*i;
    int tot = (d>>5)*4*512;
    k_wfrag<<<(tot+255)/256,256,0,stream>>>(Wl[i], WfL[i], d, 4, HH);
  }
  { int tot = (XDIM>>5)*3*512;
    k_wfrag<<<(tot+255)/256,256,0,stream>>>(Wlin, WfLin, XDIM, 3, CC); }

  int gb = (N+63)/64;
  int ab = (N+3)/4;
  for (int i=0;i<LL;i++){
    k_gemm<<<gb,256,0,stream>>>(X, WfL[i], dinv, lin, N, (FF+HH*i)>>5);
    k_agg <<<ab,256,0,stream>>>(lin, offs, esrc, dinv, bl[i], X, FF+HH*i, N);
  }
  k_final<<<gb,256,0,stream>>>(X, WfLin, blin, out, N);
}

// Round 5
// 734.203 us; speedup vs baseline: 1.9177x; 1.0649x over previous
//
#include <hip/hip_runtime.h>
#include <hip/hip_bf16.h>

#define HH 64
#define XDIM 896
#define FF 512
#define LL 6
#define CC 40

typedef __bf16 bf16x8 __attribute__((ext_vector_type(8)));
typedef float f32x4 __attribute__((ext_vector_type(4)));

__device__ __forceinline__ float bf2f(unsigned short u){
  union{unsigned int u; float f;} v; v.u = ((unsigned int)u)<<16; return v.f;
}
__device__ __forceinline__ unsigned short f2bf(float f){
  union{float f; unsigned int u;} v; v.f=f; unsigned int u=v.u;
  return (unsigned short)((u + 0x7fffu + ((u>>16)&1u))>>16);
}
__device__ __forceinline__ float u2f(unsigned u){
  union{unsigned u; float f;} v; v.u=u; return v.f;
}

// ---- degree count ----
__global__ void __launch_bounds__(256) k_count(const int* __restrict__ ei, int E, int* __restrict__ cnt){
  int i = blockIdx.x*blockDim.x + threadIdx.x;
  int stride = gridDim.x*blockDim.x;
  for (; i < E; i += stride) atomicAdd(&cnt[ei[E+i]], 1);
}

// ---- scan phase 1 (+ dinv fused) ----
__global__ void __launch_bounds__(256) k_scan1(const int* __restrict__ cnt, int* __restrict__ offs,
                                               int* __restrict__ bsum, float* __restrict__ dinv, int N){
  __shared__ int s[256];
  int t=threadIdx.x, gid=blockIdx.x*256+t;
  int v = (gid<N)? cnt[gid] : 0;
  if (gid<N) dinv[gid] = rsqrtf((float)(v+1));
  s[t]=v; __syncthreads();
  for (int o=1;o<256;o<<=1){ int x=(t>=o)?s[t-o]:0; __syncthreads(); s[t]+=x; __syncthreads(); }
  if (gid<N) offs[gid]=s[t]-v;
  if (t==255) bsum[blockIdx.x]=s[t];
}

__global__ void __launch_bounds__(512) k_scan2(int* __restrict__ bsum, int nb){
  __shared__ int s[512];
  int t=threadIdx.x;
  int v=(t<nb)?bsum[t]:0; s[t]=v; __syncthreads();
  for(int o=1;o<512;o<<=1){ int x=(t>=o)?s[t-o]:0; __syncthreads(); s[t]+=x; __syncthreads(); }
  if (t<nb) bsum[t]=s[t]-v;
}

// ---- scan phase 3 (+ bucket cursor init fused) ----
__global__ void __launch_bounds__(256) k_scan3(int* __restrict__ offs, const int* __restrict__ bsum,
                                               int* __restrict__ bcur, int N, int E){
  int gid=blockIdx.x*256+threadIdx.x;
  if (gid<N){
    int o=offs[gid]+bsum[gid>>8];
    offs[gid]=o;
    if ((gid&15)==0) bcur[gid>>4]=o;
  }
  if (gid==0) offs[N]=E;
}

// ---- pass B: bucket-partition edges (bucket = 16 nodes) ----
__global__ void __launch_bounds__(256) k_bfill(const int* __restrict__ ei, int E,
                                               int* __restrict__ bcur, unsigned* __restrict__ tmp){
  int i = blockIdx.x*blockDim.x + threadIdx.x;
  int stride = gridDim.x*blockDim.x;
  for (; i<E; i+=stride){
    int r = ei[i], c = ei[E+i];
    int pos = atomicAdd(&bcur[c>>4], 1);
    tmp[pos] = ((unsigned)r<<4) | (unsigned)(c & 15);
  }
}

// ---- pass C: within-bucket scatter, LDS cursors (block owns its bucket) ----
__global__ void __launch_bounds__(256) k_scatter(const unsigned* __restrict__ tmp,
                                                 const int* __restrict__ offs,
                                                 int* __restrict__ esrc, int N){
  __shared__ int cur[16];
  int b = blockIdx.x;
  int n0 = b*16;
  int n1 = n0+16; if (n1 > N) n1 = N;
  if (threadIdx.x < 16 && n0 + threadIdx.x < n1)
    cur[threadIdx.x] = offs[n0 + threadIdx.x];
  __syncthreads();
  int start = offs[n0], end = offs[n1];
  for (int i = start + threadIdx.x; i < end; i += 256){
    unsigned v = tmp[i];
    int c = (int)(v & 15u);
    int r = (int)(v >> 4);
    int pos = atomicAdd(&cur[c], 1);
    esrc[pos] = r;
  }
}

// ---- x -> bf16 into X[:, 0:512]; also zero lin's row N ----
__global__ void __launch_bounds__(256) k_xcast(const float* __restrict__ x, unsigned short* __restrict__ X,
                                               unsigned short* __restrict__ lin, int N){
  int i = blockIdx.x*blockDim.x + threadIdx.x; // one thread per 4 floats
  if (i < 32) ((unsigned*)(lin + (size_t)N*64))[i] = 0u;
  int total = N*(FF/4);
  if (i >= total) return;
  int row = i/(FF/4), c4 = (i%(FF/4))*4;
  float4 v = *(const float4*)(x + (size_t)row*FF + c4);
  ushort4 o; o.x=f2bf(v.x); o.y=f2bf(v.y); o.z=f2bf(v.z); o.w=f2bf(v.w);
  *(ushort4*)(X + (size_t)row*XDIM + c4) = o;
}

// ---- all W (fp32 [d][ncols]) -> bf16 MFMA B-fragment layout, one launch ----
struct WfA {
  const float* W[7];
  unsigned short* dst[7];
  int nt[7], nc[7];
  int off[8];
};
__global__ void __launch_bounds__(256) k_wfrag(WfA A){
  int idx = blockIdx.x*256 + threadIdx.x;
  if (idx >= A.off[7]) return;
  int seg = 0;
  while (idx >= A.off[seg+1]) ++seg;
  int li = idx - A.off[seg];
  int j = li&7, lane=(li>>3)&63, rem=li>>9;
  int ntile = A.nt[seg], ncols = A.nc[seg];
  int nt = rem % ntile, kb = rem / ntile;
  int k = kb*32 + (lane>>4)*8 + j;
  int c = nt*16 + (lane&15);
  float v = (c<ncols)? A.W[seg][(size_t)k*ncols + c] : 0.f;
  A.dst[seg][li]=f2bf(v);
}

// ---- lin[N,64] = (X[:, :32*nkb] @ Wf) * dinv[row] ; 4 waves/block, 32 rows/wave ----
__global__ void __launch_bounds__(256) k_gemm(const unsigned short* __restrict__ X,
                                              const unsigned short* __restrict__ Wf,
                                              const float* __restrict__ dinv,
                                              unsigned short* __restrict__ lin,
                                              int N, int nkb){
  int lane = threadIdx.x & 63, wid = threadIdx.x >> 6;
  long row0 = (long)blockIdx.x*128 + wid*32;
  int arow = lane & 15, kgrp = lane >> 4;
  long r0 = row0 + arow;      if (r0 > (long)N-1) r0 = N-1;
  long r1 = row0 + 16 + arow; if (r1 > (long)N-1) r1 = N-1;
  const unsigned short* ap0 = X + (size_t)r0*XDIM + kgrp*8;
  const unsigned short* ap1 = X + (size_t)r1*XDIM + kgrp*8;
  const unsigned short* bptr = Wf + lane*8;
  f32x4 acc00={0.f,0.f,0.f,0.f}, acc01=acc00, acc02=acc00, acc03=acc00;
  f32x4 acc10=acc00, acc11=acc00, acc12=acc00, acc13=acc00;
  for (int kb=0; kb<nkb; ++kb){
    bf16x8 a0 = *(const bf16x8*)(ap0 + (size_t)kb*32);
    bf16x8 a1 = *(const bf16x8*)(ap1 + (size_t)kb*32);
    const unsigned short* bp = bptr + (size_t)kb*2048;
    bf16x8 b0=*(const bf16x8*)bp, b1=*(const bf16x8*)(bp+512),
           b2=*(const bf16x8*)(bp+1024), b3=*(const bf16x8*)(bp+1536);
    acc00=__builtin_amdgcn_mfma_f32_16x16x32_bf16(a0,b0,acc00,0,0,0);
    acc10=__builtin_amdgcn_mfma_f32_16x16x32_bf16(a1,b0,acc10,0,0,0);
    acc01=__builtin_amdgcn_mfma_f32_16x16x32_bf16(a0,b1,acc01,0,0,0);
    acc11=__builtin_amdgcn_mfma_f32_16x16x32_bf16(a1,b1,acc11,0,0,0);
    acc02=__builtin_amdgcn_mfma_f32_16x16x32_bf16(a0,b2,acc02,0,0,0);
    acc12=__builtin_amdgcn_mfma_f32_16x16x32_bf16(a1,b2,acc12,0,0,0);
    acc03=__builtin_amdgcn_mfma_f32_16x16x32_bf16(a0,b3,acc03,0,0,0);
    acc13=__builtin_amdgcn_mfma_f32_16x16x32_bf16(a1,b3,acc13,0,0,0);
  }
  // D: col = lane&15, row = (lane>>4)*4 + reg; scale by dinv[row]
  for (int j=0;j<4;++j){
    long rr = row0 + kgrp*4 + j;
    if (rr < N){
      float dv = dinv[rr];
      unsigned short* lp = lin + (size_t)rr*64 + arow;
      lp[0]  = f2bf(acc00[j]*dv);
      lp[16] = f2bf(acc01[j]*dv);
      lp[32] = f2bf(acc02[j]*dv);
      lp[48] = f2bf(acc03[j]*dv);
    }
    long rr1 = rr + 16;
    if (rr1 < N){
      float dv = dinv[rr1];
      unsigned short* lp = lin + (size_t)rr1*64 + arow;
      lp[0]  = f2bf(acc10[j]*dv);
      lp[16] = f2bf(acc11[j]*dv);
      lp[32] = f2bf(acc12[j]*dv);
      lp[48] = f2bf(acc13[j]*dv);
    }
  }
}

// ---- aggregate: 1 wave/node; lane = (sub=edge-slot 0..3, fq=feature-quad 0..15) ----
// group k covers 4 edges; lane's source index via direct esrc dword (L1 broadcast).
// 8 groups (32 edges) in flight per unrolled body; tail masked to zero row lin[N].
__global__ void __launch_bounds__(256) k_agg(const unsigned short* __restrict__ lin,
                                             const int* __restrict__ offs,
                                             const int* __restrict__ esrc,
                                             const float* __restrict__ dinv,
                                             const float* __restrict__ bias,
                                             unsigned short* __restrict__ X,
                                             int colbase, int N){
  int lane = threadIdx.x & 63, wid = threadIdx.x >> 6;
  int n = blockIdx.x*4 + wid;
  if (n >= N) return;
  int sub = lane >> 4;
  int fq  = lane & 15;
  const unsigned short* lq = lin + fq*4;
  float a0=0.f, a1=0.f, a2=0.f, a3=0.f;
  int s = offs[n], e = offs[n+1];
  int base = s;
  for (; base + 32 <= e; base += 32){
    #pragma unroll
    for (int k=0;k<8;++k){
      int sx = esrc[base + 4*k + sub];
      uint2 v = *(const uint2*)(lq + (size_t)sx*64);
      a0 += u2f(v.x<<16); a1 += u2f(v.x&0xffff0000u);
      a2 += u2f(v.y<<16); a3 += u2f(v.y&0xffff0000u);
    }
  }
  if (base < e){
    int rem = e - base;     // 1..31
    if (rem > 16){
      #pragma unroll
      for (int k=0;k<8;++k){
        int idx = 4*k + sub;
        int sx = esrc[base + idx];
        sx = (idx < rem) ? sx : (int)N;
        uint2 v = *(const uint2*)(lq + (size_t)sx*64);
        a0 += u2f(v.x<<16); a1 += u2f(v.x&0xffff0000u);
        a2 += u2f(v.y<<16); a3 += u2f(v.y&0xffff0000u);
      }
    } else {
      #pragma unroll
      for (int k=0;k<4;++k){
        int idx = 4*k + sub;
        int sx = esrc[base + idx];
        sx = (idx < rem) ? sx : (int)N;
        uint2 v = *(const uint2*)(lq + (size_t)sx*64);
        a0 += u2f(v.x<<16); a1 += u2f(v.x&0xffff0000u);
        a2 += u2f(v.y<<16); a3 += u2f(v.y&0xffff0000u);
      }
    }
  }
  // reduce across the 4 edge slots (bits 4,5 of lane)
  a0 += __shfl_xor(a0,16,64); a0 += __shfl_xor(a0,32,64);
  a1 += __shfl_xor(a1,16,64); a1 += __shfl_xor(a1,32,64);
  a2 += __shfl_xor(a2,16,64); a2 += __shfl_xor(a2,32,64);
  a3 += __shfl_xor(a3,16,64); a3 += __shfl_xor(a3,32,64);
  // self-loop (added once, after reduction)
  uint2 vs = *(const uint2*)(lq + (size_t)n*64);
  a0 += u2f(vs.x<<16); a1 += u2f(vs.x&0xffff0000u);
  a2 += u2f(vs.y<<16); a3 += u2f(vs.y&0xffff0000u);
  float dv = dinv[n];
  float4 b4 = *(const float4*)(bias + fq*4);
  float h0 = fmaxf(a0*dv + b4.x, 0.f);
  float h1 = fmaxf(a1*dv + b4.y, 0.f);
  float h2 = fmaxf(a2*dv + b4.z, 0.f);
  float h3 = fmaxf(a3*dv + b4.w, 0.f);
  if (sub == 0){
    ushort4 o; o.x=f2bf(h0); o.y=f2bf(h1); o.z=f2bf(h2); o.w=f2bf(h3);
    *(ushort4*)(X + (size_t)n*XDIM + colbase + fq*4) = o;
  }
}

// ---- final: logits = X @ Wlin + blin, log_softmax, write fp32 [N,40] ----
__global__ void __launch_bounds__(256) k_final(const unsigned short* __restrict__ X,
                                               const unsigned short* __restrict__ Wf,
                                               const float* __restrict__ blin,
                                               float* __restrict__ out, int N){
  int lane=threadIdx.x&63, wid=threadIdx.x>>6;
  long row0=(long)blockIdx.x*64 + wid*16;
  int c0=lane&15, g=lane>>4;
  long r=row0+c0; if (r > (long)N-1) r = N-1;
  const unsigned short* aptr = X + (size_t)r*XDIM + g*8;
  const unsigned short* bptr = Wf + lane*8;
  f32x4 acc0={0.f,0.f,0.f,0.f}, acc1=acc0, acc2=acc0;
  const int nkb = XDIM/32; // 28
  for (int kb=0;kb<nkb;++kb){
    bf16x8 a=*(const bf16x8*)(aptr+(size_t)kb*32);
    const unsigned short* bp = bptr + (size_t)kb*1536;
    bf16x8 b0=*(const bf16x8*)bp, b1=*(const bf16x8*)(bp+512), b2=*(const bf16x8*)(bp+1024);
    acc0=__builtin_amdgcn_mfma_f32_16x16x32_bf16(a,b0,acc0,0,0,0);
    acc1=__builtin_amdgcn_mfma_f32_16x16x32_bf16(a,b1,acc1,0,0,0);
    acc2=__builtin_amdgcn_mfma_f32_16x16x32_bf16(a,b2,acc2,0,0,0);
  }
  float bl0 = blin[c0], bl1 = blin[16+c0];
  bool v2ok = (c0 < 8);
  float bl2 = v2ok ? blin[32+c0] : 0.f;
  for (int j=0;j<4;++j){
    long rr = row0 + g*4 + j;
    float v0 = acc0[j]+bl0, v1 = acc1[j]+bl1;
    float v2 = v2ok ? (acc2[j]+bl2) : -1e30f;
    float m = fmaxf(fmaxf(v0,v1),v2);
    m = fmaxf(m, __shfl_xor(m,1,64));
    m = fmaxf(m, __shfl_xor(m,2,64));
    m = fmaxf(m, __shfl_xor(m,4,64));
    m = fmaxf(m, __shfl_xor(m,8,64));
    float sEx = expf(v0-m)+expf(v1-m)+(v2ok?expf(v2-m):0.f);
    sEx += __shfl_xor(sEx,1,64);
    sEx += __shfl_xor(sEx,2,64);
    sEx += __shfl_xor(sEx,4,64);
    sEx += __shfl_xor(sEx,8,64);
    float lse = m + logf(sEx);
    if (rr < N){
      out[(size_t)rr*CC + c0]      = v0 - lse;
      out[(size_t)rr*CC + 16 + c0] = v1 - lse;
      if (v2ok) out[(size_t)rr*CC + 32 + c0] = v2 - lse;
    }
  }
}

extern "C" void kernel_launch(void* const* d_in, const int* in_sizes, int n_in,
                              void* d_out, int out_size, void* d_ws, size_t ws_size,
                              hipStream_t stream){
  const float* x = (const float*)d_in[0];
  const int* ei = (const int*)d_in[1];
  const float* Wl[LL]; const float* bl[LL];
  for (int i=0;i<LL;i++){ Wl[i]=(const float*)d_in[2+2*i]; bl[i]=(const float*)d_in[3+2*i]; }
  const float* Wlin = (const float*)d_in[2+2*LL];
  const float* blin = (const float*)d_in[3+2*LL];
  float* out = (float*)d_out;
  const int N = in_sizes[0]/FF;
  const int E = in_sizes[1]/2;
  const int nbk = (N+15)/16;

  char* p = (char*)d_ws;
  auto alloc = [&](size_t b)->char*{ char* r=p; p += (b+255)&~(size_t)255; return r; };
  unsigned short* X   = (unsigned short*)alloc((size_t)N*XDIM*2);
  unsigned short* lin = (unsigned short*)alloc((size_t)(N+1)*64*2);  // +1 zero row
  unsigned* tmp = (unsigned*)lin;  // alias: tmp (E*4B) used only before GEMM phase
  unsigned short* WfL[LL];
  for (int i=0;i<LL;i++){ int d=FF+HH*i; WfL[i]=(unsigned short*)alloc((size_t)d*64*2); }
  unsigned short* WfLin = (unsigned short*)alloc((size_t)XDIM*48*2);
  float* dinv = (float*)alloc((size_t)N*4);
  int* cnt    = (int*)alloc((size_t)N*4);
  int* offs   = (int*)alloc((size_t)(N+1)*4);
  int* bcur   = (int*)alloc((size_t)nbk*4);
  int* bsum   = (int*)alloc(512*4);
  int* esrc   = (int*)alloc((size_t)(E+64)*4);  // +64 pad for unrolled tail reads

  hipMemsetAsync(cnt, 0, (size_t)N*4, stream);

  int nb = (N+255)/256;
  k_count<<<2048, 256, 0, stream>>>(ei, E, cnt);
  k_scan1<<<nb, 256, 0, stream>>>(cnt, offs, bsum, dinv, N);
  k_scan2<<<1, 512, 0, stream>>>(bsum, nb);
  k_scan3<<<nb, 256, 0, stream>>>(offs, bsum, bcur, N, E);
  k_bfill<<<2048, 256, 0, stream>>>(ei, E, bcur, tmp);
  k_scatter<<<nbk, 256, 0, stream>>>(tmp, offs, esrc, N);
  k_xcast<<<(N*(FF/4)+255)/256, 256, 0, stream>>>(x, X, lin, N);

  WfA A;
  int off = 0;
  for (int i=0;i<LL;i++){
    int d = FF+HH*i;
    A.W[i]=Wl[i]; A.dst[i]=WfL[i]; A.nt[i]=4; A.nc[i]=HH;
    A.off[i]=off; off += (d>>5)*4*512;
  }
  A.W[LL]=Wlin; A.dst[LL]=WfLin; A.nt[LL]=3; A.nc[LL]=CC;
  A.off[LL]=off; off += (XDIM>>5)*3*512;
  A.off[LL+1]=off;
  k_wfrag<<<(off+255)/256, 256, 0, stream>>>(A);

  int gb = (N+127)/128;
  int ab = (N+3)/4;
  for (int i=0;i<LL;i++){
    k_gemm<<<gb,256,0,stream>>>(X, WfL[i], dinv, lin, N, (FF+HH*i)>>5);
    k_agg <<<ab,256,0,stream>>>(lin, offs, esrc, dinv, bl[i], X, FF+HH*i, N);
  }
  k_final<<<(N+63)/64,256,0,stream>>>(X, WfLin, blin, out, N);
}